// Round 5
// baseline (265.233 us; speedup 1.0000x reference)
//
#include <hip/hip_runtime.h>
#include <float.h>
#include <math.h>

typedef __bf16 bf16;
typedef __attribute__((ext_vector_type(8))) __bf16 bf16x8;
typedef __attribute__((ext_vector_type(4))) float f32x4;
typedef long long i64;

#define MK 544  // Mg row stride (bf16); cols [0,515) real, rest zero

// workspace byte offsets
#define WS_MG   0        // bf16[16*544]   = 17408 B
#define WS_CVEC 17408    // f32[16]        = 64 B
#define WS_W1F  17472    // i64[2*2*64]    = 2048 B   (fp8 conv1 frags, x16)
#define WS_W2F  19520    // i64[4*3*64]    = 6144 B   (fp8 conv2 frags, x16)

__device__ __forceinline__ f32x4 mfma16(bf16x8 a, bf16x8 b, f32x4 c) {
  return __builtin_amdgcn_mfma_f32_16x16x32_bf16(a, b, c, 0, 0, 0);
}
__device__ __forceinline__ f32x4 mfma8(i64 a, i64 b, f32x4 c) {
  return __builtin_amdgcn_mfma_f32_16x16x32_fp8_fp8(a, b, c, 0, 0, 0);
}

// ---------------------------------------------------------------------------
// Precompute (grid 35): blocks 0..33 build Mg[n][k] (bf16; k<515 real, rest 0)
// and cvec[n]; block 34 builds fp8 weight fragment tables (both scaled x16).
// ---------------------------------------------------------------------------
__global__ __launch_bounds__(256) void acek_pre(
    const float* __restrict__ led_feats, const float* __restrict__ led_pos,
    const float* __restrict__ q_w, const float* __restrict__ q_b,
    const float* __restrict__ k_w, const float* __restrict__ k_b,
    const float* __restrict__ c1w, const float* __restrict__ c2w,
    char* __restrict__ ws) {
  bf16* Mg = (bf16*)(ws + WS_MG);
  float* cvec = (float*)(ws + WS_CVEC);
  i64* W1F = (i64*)(ws + WS_W1F);
  i64* W2F = (i64*)(ws + WS_W2F);
  const int t = threadIdx.x;

  if (blockIdx.x == 34) {
    {  // conv1 fp8 frags: idx (ot*2+s)*64+lane; elem j <-> k1 = s*32+g*8+j
      int ot = t >> 7, s = (t >> 6) & 1, lane = t & 63;
      int g = lane >> 4, a15 = lane & 15;
      float v[8];
#pragma unroll
      for (int j = 0; j < 8; ++j) {
        int k1 = s * 32 + g * 8 + j;
        int dk = k1 >> 4, ic = k1 & 15;
        v[j] = (ic < 12 && dk < 3) ? 16.f * c1w[(ot * 16 + a15) * 36 + ic * 3 + dk] : 0.f;
      }
      int lo = __builtin_amdgcn_cvt_pk_fp8_f32(v[0], v[1], 0, false);
      lo = __builtin_amdgcn_cvt_pk_fp8_f32(v[2], v[3], lo, true);
      int hi = __builtin_amdgcn_cvt_pk_fp8_f32(v[4], v[5], 0, false);
      hi = __builtin_amdgcn_cvt_pk_fp8_f32(v[6], v[7], hi, true);
      W1F[t] = ((i64)(unsigned)lo) | (((i64)hi) << 32);
    }
    for (int r = 0; r < 3; ++r) {  // conv2 fp8 frags
      int fi = t + r * 256;
      int o = fi / 192, rem = fi - o * 192;
      int s = rem >> 6, lane = rem & 63;
      int g = lane >> 4, a15 = lane & 15;
      float v[8];
#pragma unroll
      for (int j = 0; j < 8; ++j)
        v[j] = 16.f * c2w[(o * 16 + a15) * 96 + (g * 8 + j) * 3 + s];
      int lo = __builtin_amdgcn_cvt_pk_fp8_f32(v[0], v[1], 0, false);
      lo = __builtin_amdgcn_cvt_pk_fp8_f32(v[2], v[3], lo, true);
      int hi = __builtin_amdgcn_cvt_pk_fp8_f32(v[4], v[5], 0, false);
      hi = __builtin_amdgcn_cvt_pk_fp8_f32(v[6], v[7], hi, true);
      W2F[fi] = ((i64)(unsigned)lo) | (((i64)hi) << 32);
    }
    return;
  }

  __shared__ float keys[16 * 64];
  for (int idx = t; idx < 16 * 64; idx += 256) {
    int n = idx >> 6, d = idx & 63;
    float acc = k_b[d];
#pragma unroll
    for (int j = 0; j < 8; ++j) acc += k_w[d * 11 + j] * led_feats[n * 8 + j];
#pragma unroll
    for (int j = 0; j < 3; ++j) acc += k_w[d * 11 + 8 + j] * led_pos[n * 3 + j];
    keys[idx] = acc;
  }
  __syncthreads();
  int e = blockIdx.x * 256 + t;
  if (e < 16 * MK) {
    int n = e / MK, k = e - n * MK;
    float v = 0.f;
    if (k < 515) {
#pragma unroll 4
      for (int d = 0; d < 64; ++d) v += q_w[d * 515 + k] * keys[n * 64 + d];
    }
    Mg[e] = (bf16)v;
  }
  if (blockIdx.x == 0 && t < 16) {
    float acc = 0.f;
    for (int d = 0; d < 64; ++d) acc += q_b[d] * keys[t * 64 + d];
    cvec[t] = acc;
  }
}

// ---------------------------------------------------------------------------
// Main: one block per batch element; 4 waves; 25.8 KB LDS -> 6 blocks/CU.
// pre-B : waves 0-2 conv1 (11/11/10 tiles, fp8 MFMA from fp8 xw);
//         wave 3: scores (global f32 A-frags) + softmax + s_agg
// post-B: all waves conv2 (fp8) + pooled-mean reduce (tfp overlays dead xw)
// post-C: t_feat finalize + spread s_feat; barrier D; spread fusion GEMV
// ---------------------------------------------------------------------------
__global__ __launch_bounds__(256, 6) void acek_main(
    const float* __restrict__ rss, const float* __restrict__ anchor,
    const float* __restrict__ ledf, const float* __restrict__ ledp,
    const int* __restrict__ fmask,
    const float* __restrict__ c1b, const float* __restrict__ c2b,
    const float* __restrict__ rw, const float* __restrict__ rb,
    const float* __restrict__ fw, const float* __restrict__ fb,
    const bf16* __restrict__ Mg, const float* __restrict__ cvec,
    const i64* __restrict__ W1F, const i64* __restrict__ W2F,
    float* __restrict__ out) {

  // xw8: x fp8 (x16), rows 0..514 (row = w+1), 16 cols (12 real, 4 zero),
  //      16 B rows. rows 0,513,514 zero.
  // h1 : relu(conv1) fp8 [rho][oc], rho = w+1 (row 0 zero), 32 B rows,
  //      8B-block XOR swizzle: block ^= (rho>>2)&3.
  __shared__ __align__(16) unsigned char xw8[515 * 16];
  __shared__ __align__(16) unsigned char h1[513 * 32];
  __shared__ __align__(16) float att[192];
  __shared__ __align__(16) float sagg[96];
  // overlays on xw8 (dead after barrier B):
  float* tfp = (float*)xw8;            // 256 f32, written post-B
  float* comb = (float*)(xw8 + 4096);  // 128 f32, written post-C

  const int tid = threadIdx.x;
  const int lane = tid & 63;
  const int wv = tid >> 6;
  const int a15 = lane & 15;
  const int g = lane >> 4;
  const int b = blockIdx.x;
  char* xwb = (char*)xw8;
  char* h1b = (char*)h1;

  // ---- phase 0: fragment/bias loads, zero pads, stage x (fp8, x16) ----
  i64 w1f[2][2];
#pragma unroll
  for (int ot = 0; ot < 2; ++ot)
#pragma unroll
    for (int s = 0; s < 2; ++s) w1f[ot][s] = W1F[(ot * 2 + s) * 64 + lane];
  i64 w2f[4][3];
#pragma unroll
  for (int o = 0; o < 4; ++o)
#pragma unroll
    for (int s = 0; s < 3; ++s) w2f[o][s] = W2F[(o * 3 + s) * 64 + lane];
  f32x4 b1v[2], b2s[4];
#pragma unroll
  for (int ot = 0; ot < 2; ++ot) b1v[ot] = *(const f32x4*)&c1b[ot * 16 + g * 4];
#pragma unroll
  for (int o = 0; o < 4; ++o) {
    f32x4 tmp = *(const f32x4*)&c2b[o * 16 + g * 4];
    b2s[o] = tmp * 16.f;  // conv2 fp8 weight scale folded into bias
  }

  for (int r = tid; r < 515; r += 256) *(int*)(xwb + r * 16 + 12) = 0;  // cols 12-15
  if (tid < 12) {  // rows 0, 513, 514 full
    int rr = (tid >> 2) == 0 ? 0 : ((tid >> 2) == 1 ? 513 : 514);
    *(int*)(xwb + rr * 16 + (tid & 3) * 4) = 0;
  }
  if (tid < 4) *(i64*)(h1b + tid * 8) = 0;  // h1 row 0 (32 B)

  const float* xb = rss + (size_t)b * 6144;
#pragma unroll
  for (int i = 0; i < 6; ++i) {
    int f = tid + i * 256;
    f32x4 v = ((const f32x4*)xb)[f];
    int w = f / 3;
    int c = (f - w * 3) * 4;  // {0,4,8}
    int pk = __builtin_amdgcn_cvt_pk_fp8_f32(16.f * v[0], 16.f * v[1], 0, false);
    pk = __builtin_amdgcn_cvt_pk_fp8_f32(16.f * v[2], 16.f * v[3], pk, true);
    *(int*)(xwb + (w + 1) * 16 + c) = pk;
  }
  __syncthreads();  // barrier A

  // conv1 tile body (fp8): A slot j <-> k1 = s*32+g*8+j; dk=k1>>4, ic=k1&15
  auto conv1_tile = [&](int wt) {
    const int wcol = wt * 16 + a15;
    f32x4 c0 = {0.f, 0.f, 0.f, 0.f}, c1 = {0.f, 0.f, 0.f, 0.f};
#pragma unroll
    for (int s = 0; s < 2; ++s) {
      int row = wcol + 2 * s + (g >> 1);
      i64 bv = *(const i64*)(xwb + row * 16 + ((g & 1) << 3));
      c0 = mfma8(w1f[0][s], bv, c0);
      c1 = mfma8(w1f[1][s], bv, c1);
    }
    const int hrow = wcol + 1;
    const int swz = (hrow >> 2) & 3;
    const int off0 = ((((g >> 1) + 0) ^ swz) << 3) | ((g & 1) << 2);
    const int off1 = ((((g >> 1) + 2) ^ swz) << 3) | ((g & 1) << 2);
    // acc = 256*true (x16 * w16); h1 = relu(acc/256 + b1), stored unscaled fp8
    float v0 = fmaxf(fmaf(c0[0], 0.00390625f, b1v[0][0]), 0.f);
    float v1 = fmaxf(fmaf(c0[1], 0.00390625f, b1v[0][1]), 0.f);
    float v2 = fmaxf(fmaf(c0[2], 0.00390625f, b1v[0][2]), 0.f);
    float v3 = fmaxf(fmaf(c0[3], 0.00390625f, b1v[0][3]), 0.f);
    int pk0 = __builtin_amdgcn_cvt_pk_fp8_f32(v0, v1, 0, false);
    pk0 = __builtin_amdgcn_cvt_pk_fp8_f32(v2, v3, pk0, true);
    *(int*)(h1b + hrow * 32 + off0) = pk0;
    v0 = fmaxf(fmaf(c1[0], 0.00390625f, b1v[1][0]), 0.f);
    v1 = fmaxf(fmaf(c1[1], 0.00390625f, b1v[1][1]), 0.f);
    v2 = fmaxf(fmaf(c1[2], 0.00390625f, b1v[1][2]), 0.f);
    v3 = fmaxf(fmaf(c1[3], 0.00390625f, b1v[1][3]), 0.f);
    int pk1 = __builtin_amdgcn_cvt_pk_fp8_f32(v0, v1, 0, false);
    pk1 = __builtin_amdgcn_cvt_pk_fp8_f32(v2, v3, pk1, true);
    *(int*)(h1b + hrow * 32 + off1) = pk1;
  };

  if (wv < 3) {
    const int base = wv * 11;
    const int n = (wv == 2) ? 10 : 11;
    for (int t = 0; t < n; ++t) conv1_tile(base + t);
  } else {
    // ---- wave 3: scores (global f32 A-frags, bf16) + softmax + s_agg ----
    const float anc0 = anchor[(size_t)b * 3 + 0];
    const float anc1 = anchor[(size_t)b * 3 + 1];
    const float anc2 = anchor[(size_t)b * 3 + 2];
    const int rcl = (a15 < 12) ? a15 : 11;
    const bf16* MgR = Mg + a15 * MK;
    f32x4 sac = {0.f, 0.f, 0.f, 0.f};
#pragma unroll 4
    for (int s = 0; s < 16; ++s) {
      const float* xs = xb + (s * 32 + g * 8) * 12 + rcl;
      bf16x8 av;
#pragma unroll
      for (int j = 0; j < 8; ++j) av[j] = (bf16)xs[j * 12];
      bf16x8 bm = *(const bf16x8*)&MgR[s * 32 + g * 8];
      sac = mfma16(av, bm, sac);
    }
    {  // k-step 16: slots 512..514 = anchor; rest zero (Mg zero there too)
      bf16x8 av = {(bf16)0.f, (bf16)0.f, (bf16)0.f, (bf16)0.f,
                   (bf16)0.f, (bf16)0.f, (bf16)0.f, (bf16)0.f};
      if (g == 0) { av[0] = (bf16)anc0; av[1] = (bf16)anc1; av[2] = (bf16)anc2; }
      bf16x8 bm = *(const bf16x8*)&MgR[512 + g * 8];
      sac = mfma16(av, bm, sac);
    }
    float dx = anc0 - ledp[a15 * 3 + 0];
    float dy = anc1 - ledp[a15 * 3 + 1];
    float dz = anc2 - ledp[a15 * 3 + 2];
    float cv = cvec[a15] - 0.5f * __logf(dx * dx + dy * dy + dz * dz + 1e-8f);
#pragma unroll
    for (int rho = 0; rho < 4; ++rho) {
      int r = 4 * g + rho;
      int mrow = (r < 12) ? r : 11;
      float sc = sac[rho] + cv;
      if (fmask[mrow * 16 + a15] == 0) sc = -FLT_MAX;
      float mx = sc;
      mx = fmaxf(mx, __shfl_xor(mx, 1, 16));
      mx = fmaxf(mx, __shfl_xor(mx, 2, 16));
      mx = fmaxf(mx, __shfl_xor(mx, 4, 16));
      mx = fmaxf(mx, __shfl_xor(mx, 8, 16));
      float ev = __expf(sc - mx);
      float sm = ev;
      sm += __shfl_xor(sm, 1, 16);
      sm += __shfl_xor(sm, 2, 16);
      sm += __shfl_xor(sm, 4, 16);
      sm += __shfl_xor(sm, 8, 16);
      if (r < 12) att[r * 16 + a15] = ev / sm;
    }
    for (int it = lane; it < 96; it += 64) {  // s_agg
      int r = it >> 3, f = it & 7;
      float acc = 0.f;
#pragma unroll
      for (int n = 0; n < 16; ++n) acc += att[r * 16 + n] * ledf[n * 8 + f];
      sagg[it] = acc;
    }
  }
  __syncthreads();  // barrier B  (xw8 dead from here; tfp/comb overlay it)

  // ---- post-B: conv2 (fp8 MFMA, swizzled h1 reads) + pooled mean ----
  {
    float tacc[4][4] = {{0.f, 0.f, 0.f, 0.f}, {0.f, 0.f, 0.f, 0.f},
                        {0.f, 0.f, 0.f, 0.f}, {0.f, 0.f, 0.f, 0.f}};
#pragma unroll
    for (int pti = 0; pti < 4; ++pti) {
      const int p = (wv * 4 + pti) * 16 + a15;
      f32x4 cc0 = {0.f, 0.f, 0.f, 0.f}, cc1 = {0.f, 0.f, 0.f, 0.f};
      f32x4 cc2 = {0.f, 0.f, 0.f, 0.f}, cc3 = {0.f, 0.f, 0.f, 0.f};
#pragma unroll
      for (int s = 0; s < 3; ++s) {
        const int rho = 2 * p + s;
        i64 hv = *(const i64*)(h1b + rho * 32 + ((g ^ ((rho >> 2) & 3)) << 3));
        cc0 = mfma8(w2f[0][s], hv, cc0);
        cc1 = mfma8(w2f[1][s], hv, cc1);
        cc2 = mfma8(w2f[2][s], hv, cc2);
        cc3 = mfma8(w2f[3][s], hv, cc3);
      }
#pragma unroll
      for (int r = 0; r < 4; ++r) {
        tacc[0][r] += fmaxf(cc0[r] + b2s[0][r], 0.f);
        tacc[1][r] += fmaxf(cc1[r] + b2s[1][r], 0.f);
        tacc[2][r] += fmaxf(cc2[r] + b2s[2][r], 0.f);
        tacc[3][r] += fmaxf(cc3[r] + b2s[3][r], 0.f);
      }
    }
#pragma unroll
    for (int o = 0; o < 4; ++o)
#pragma unroll
      for (int r = 0; r < 4; ++r) {
        float v = tacc[o][r];
        v += __shfl_xor(v, 1, 16);
        v += __shfl_xor(v, 2, 16);
        v += __shfl_xor(v, 4, 16);
        v += __shfl_xor(v, 8, 16);
        if (a15 == 0) tfp[wv * 64 + o * 16 + g * 4 + r] = v;
      }
  }
  __syncthreads();  // barrier C

  // ---- post-C: t_feat finalize + spread s_feat ----
  if (tid < 64)
    comb[tid] = (tfp[tid] + tfp[64 + tid] + tfp[128 + tid] + tfp[192 + tid]) *
                (1.f / 4096.f);  // /256 mean * /16 conv2 fp8 scale
  {
    const int o = tid >> 2, q = tid & 3;
    float acc = 0.f;
    const f32x4* rwv = (const f32x4*)(rw + o * 96 + q * 24);
    const f32x4* sv = (const f32x4*)(sagg + q * 24);
#pragma unroll
    for (int i = 0; i < 6; ++i) {
      f32x4 a = rwv[i], s = sv[i];
      acc += a[0] * s[0] + a[1] * s[1] + a[2] * s[2] + a[3] * s[3];
    }
    acc += __shfl_xor(acc, 1, 4);
    acc += __shfl_xor(acc, 2, 4);
    if (q == 0) comb[64 + o] = fmaxf(acc + rb[o], 0.f);
  }
  __syncthreads();  // barrier D

  // ---- spread fusion GEMV: out = fus_w @ comb + fus_b ----
  {
    const int o = tid >> 2, q = tid & 3;
    float acc = 0.f;
    const f32x4* fwv = (const f32x4*)(fw + o * 128 + q * 32);
    const f32x4* cv = (const f32x4*)(comb + q * 32);
#pragma unroll
    for (int i = 0; i < 8; ++i) {
      f32x4 a = fwv[i], c = cv[i];
      acc += a[0] * c[0] + a[1] * c[1] + a[2] * c[2] + a[3] * c[3];
    }
    acc += __shfl_xor(acc, 1, 4);
    acc += __shfl_xor(acc, 2, 4);
    if (q == 0) out[(size_t)b * 64 + o] = acc + fb[o];
  }
}

extern "C" void kernel_launch(void* const* d_in, const int* in_sizes, int n_in,
                              void* d_out, int out_size, void* d_ws, size_t ws_size,
                              hipStream_t stream) {
  (void)in_sizes; (void)n_in; (void)out_size; (void)ws_size;
  const float* rss   = (const float*)d_in[0];
  const float* anch  = (const float*)d_in[1];
  const float* ledf  = (const float*)d_in[2];
  const float* ledp  = (const float*)d_in[3];
  const int*   fmask = (const int*)d_in[4];
  const float* c1w = (const float*)d_in[5];
  const float* c1b = (const float*)d_in[6];
  const float* c2w = (const float*)d_in[7];
  const float* c2b = (const float*)d_in[8];
  const float* qw  = (const float*)d_in[9];
  const float* qb  = (const float*)d_in[10];
  const float* kw  = (const float*)d_in[11];
  const float* kb  = (const float*)d_in[12];
  const float* rw  = (const float*)d_in[13];
  const float* rb  = (const float*)d_in[14];
  const float* fw  = (const float*)d_in[15];
  const float* fb  = (const float*)d_in[16];
  float* outp = (float*)d_out;
  char* ws = (char*)d_ws;

  acek_pre<<<35, 256, 0, stream>>>(ledf, ledp, qw, qb, kw, kb, c1w, c2w, ws);
  acek_main<<<8192, 256, 0, stream>>>(
      rss, anch, ledf, ledp, fmask, c1b, c2b, rw, rb, fw, fb,
      (const bf16*)(ws + WS_MG), (const float*)(ws + WS_CVEC),
      (const i64*)(ws + WS_W1F), (const i64*)(ws + WS_W2F), outp);
}

// Round 6
// 139.362 us; speedup vs baseline: 1.9032x; 1.9032x over previous
//
#include <hip/hip_runtime.h>
#include <float.h>
#include <math.h>

typedef __bf16 bf16;
typedef __attribute__((ext_vector_type(8))) __bf16 bf16x8;
typedef __attribute__((ext_vector_type(4))) float f32x4;
typedef long long i64;

#define MK 544  // Mg row stride (bf16); cols [0,515) real, rest zero

// workspace byte offsets
#define WS_MG   0        // bf16[16*544]   = 17408 B
#define WS_CVEC 17408    // f32[16]        = 64 B
#define WS_W1F  17472    // i64[2*2*64]    = 2048 B   (fp8 conv1 frags, x16)
#define WS_W2F  19520    // i64[4*3*64]    = 6144 B   (fp8 conv2 frags, x16)

__device__ __forceinline__ f32x4 mfma16(bf16x8 a, bf16x8 b, f32x4 c) {
  return __builtin_amdgcn_mfma_f32_16x16x32_bf16(a, b, c, 0, 0, 0);
}
__device__ __forceinline__ f32x4 mfma8(i64 a, i64 b, f32x4 c) {
  return __builtin_amdgcn_mfma_f32_16x16x32_fp8_fp8(a, b, c, 0, 0, 0);
}

// ---------------------------------------------------------------------------
// Precompute (grid 35): blocks 0..33 build Mg[n][k] (bf16; k<515 real, rest 0)
// and cvec[n]; block 34 builds fp8 weight fragment tables (both scaled x16).
// ---------------------------------------------------------------------------
__global__ __launch_bounds__(256) void acek_pre(
    const float* __restrict__ led_feats, const float* __restrict__ led_pos,
    const float* __restrict__ q_w, const float* __restrict__ q_b,
    const float* __restrict__ k_w, const float* __restrict__ k_b,
    const float* __restrict__ c1w, const float* __restrict__ c2w,
    char* __restrict__ ws) {
  bf16* Mg = (bf16*)(ws + WS_MG);
  float* cvec = (float*)(ws + WS_CVEC);
  i64* W1F = (i64*)(ws + WS_W1F);
  i64* W2F = (i64*)(ws + WS_W2F);
  const int t = threadIdx.x;

  if (blockIdx.x == 34) {
    {  // conv1 fp8 frags: idx (ot*2+s)*64+lane; elem j <-> k1 = s*32+g*8+j
      int ot = t >> 7, s = (t >> 6) & 1, lane = t & 63;
      int g = lane >> 4, a15 = lane & 15;
      float v[8];
#pragma unroll
      for (int j = 0; j < 8; ++j) {
        int k1 = s * 32 + g * 8 + j;
        int dk = k1 >> 4, ic = k1 & 15;
        v[j] = (ic < 12 && dk < 3) ? 16.f * c1w[(ot * 16 + a15) * 36 + ic * 3 + dk] : 0.f;
      }
      int lo = __builtin_amdgcn_cvt_pk_fp8_f32(v[0], v[1], 0, false);
      lo = __builtin_amdgcn_cvt_pk_fp8_f32(v[2], v[3], lo, true);
      int hi = __builtin_amdgcn_cvt_pk_fp8_f32(v[4], v[5], 0, false);
      hi = __builtin_amdgcn_cvt_pk_fp8_f32(v[6], v[7], hi, true);
      W1F[t] = ((i64)(unsigned)lo) | (((i64)hi) << 32);
    }
    for (int r = 0; r < 3; ++r) {  // conv2 fp8 frags
      int fi = t + r * 256;
      int o = fi / 192, rem = fi - o * 192;
      int s = rem >> 6, lane = rem & 63;
      int g = lane >> 4, a15 = lane & 15;
      float v[8];
#pragma unroll
      for (int j = 0; j < 8; ++j)
        v[j] = 16.f * c2w[(o * 16 + a15) * 96 + (g * 8 + j) * 3 + s];
      int lo = __builtin_amdgcn_cvt_pk_fp8_f32(v[0], v[1], 0, false);
      lo = __builtin_amdgcn_cvt_pk_fp8_f32(v[2], v[3], lo, true);
      int hi = __builtin_amdgcn_cvt_pk_fp8_f32(v[4], v[5], 0, false);
      hi = __builtin_amdgcn_cvt_pk_fp8_f32(v[6], v[7], hi, true);
      W2F[fi] = ((i64)(unsigned)lo) | (((i64)hi) << 32);
    }
    return;
  }

  __shared__ float keys[16 * 64];
  for (int idx = t; idx < 16 * 64; idx += 256) {
    int n = idx >> 6, d = idx & 63;
    float acc = k_b[d];
#pragma unroll
    for (int j = 0; j < 8; ++j) acc += k_w[d * 11 + j] * led_feats[n * 8 + j];
#pragma unroll
    for (int j = 0; j < 3; ++j) acc += k_w[d * 11 + 8 + j] * led_pos[n * 3 + j];
    keys[idx] = acc;
  }
  __syncthreads();
  int e = blockIdx.x * 256 + t;
  if (e < 16 * MK) {
    int n = e / MK, k = e - n * MK;
    float v = 0.f;
    if (k < 515) {
#pragma unroll 4
      for (int d = 0; d < 64; ++d) v += q_w[d * 515 + k] * keys[n * 64 + d];
    }
    Mg[e] = (bf16)v;
  }
  if (blockIdx.x == 0 && t < 16) {
    float acc = 0.f;
    for (int d = 0; d < 64; ++d) acc += q_b[d] * keys[t * 64 + d];
    cvec[t] = acc;
  }
}

// ---------------------------------------------------------------------------
// Main: one block per batch element; 4 waves, NO wave specialization.
// pre-B : every wave: issue 32 score A-loads (global f32), conv1 x8 (fp8),
//         score MFMA x4 k-steps -> parts[wv]
// post-B: conv2 (fp8, swizzled h1) + pooled mean -> tfp
// post-C: softmax + in-group shfl s_agg (tid<192) || t_feat finalize (tid>=192)
// post-D: spread s_feat;  post-E: spread fusion GEMV
// ---------------------------------------------------------------------------
__global__ __launch_bounds__(256, 4) void acek_main(
    const float* __restrict__ rss, const float* __restrict__ anchor,
    const float* __restrict__ ledf, const float* __restrict__ ledp,
    const int* __restrict__ fmask,
    const float* __restrict__ c1b, const float* __restrict__ c2b,
    const float* __restrict__ rw, const float* __restrict__ rb,
    const float* __restrict__ fw, const float* __restrict__ fb,
    const bf16* __restrict__ Mg, const float* __restrict__ cvec,
    const i64* __restrict__ W1F, const i64* __restrict__ W2F,
    float* __restrict__ out) {

  // xw8 : x fp8 (x16), rows 0..514 (row = w+1), 16 cols (12 real), 16 B rows.
  // h1  : relu(conv1) fp8 [rho][oc], rho = w+1 (row 0 zero), 32 B rows,
  //       8B-block XOR swizzle: block ^= (rho>>2)&3.
  // parts: per-wave score partials [wv][ (g*4+rho)*16 + a15 ].
  __shared__ __align__(16) unsigned char xw8[515 * 16];
  __shared__ __align__(16) unsigned char h1[513 * 32];
  __shared__ __align__(16) float parts[1024];
  __shared__ __align__(16) float sagg[96];
  __shared__ __align__(16) float bias_lds[16];
  // overlays on xw8 (dead after barrier B):
  float* tfp = (float*)xw8;            // 256 f32, written post-B
  float* comb = (float*)(xw8 + 1024);  // 128 f32, written post-C/D

  const int tid = threadIdx.x;
  const int lane = tid & 63;
  const int wv = tid >> 6;
  const int a15 = lane & 15;
  const int g = lane >> 4;
  const int b = blockIdx.x;
  char* xwb = (char*)xw8;
  char* h1b = (char*)h1;

  // ---- phase 0: fragment/bias loads, zero pads, stage x (fp8, x16) ----
  i64 w1f[2][2];
#pragma unroll
  for (int ot = 0; ot < 2; ++ot)
#pragma unroll
    for (int s = 0; s < 2; ++s) w1f[ot][s] = W1F[(ot * 2 + s) * 64 + lane];
  i64 w2f[4][3];
#pragma unroll
  for (int o = 0; o < 4; ++o)
#pragma unroll
    for (int s = 0; s < 3; ++s) w2f[o][s] = W2F[(o * 3 + s) * 64 + lane];
  f32x4 b1v[2], b2s[4];
#pragma unroll
  for (int ot = 0; ot < 2; ++ot) b1v[ot] = *(const f32x4*)&c1b[ot * 16 + g * 4];
#pragma unroll
  for (int o = 0; o < 4; ++o) {
    f32x4 tmp = *(const f32x4*)&c2b[o * 16 + g * 4];
    b2s[o] = tmp * 16.f;  // conv2 fp8 weight scale folded into bias
  }

  for (int r = tid; r < 515; r += 256) *(int*)(xwb + r * 16 + 12) = 0;  // cols 12-15
  if (tid < 12) {  // rows 0, 513, 514 full
    int rr = (tid >> 2) == 0 ? 0 : ((tid >> 2) == 1 ? 513 : 514);
    *(int*)(xwb + rr * 16 + (tid & 3) * 4) = 0;
  }
  if (tid < 4) *(i64*)(h1b + tid * 8) = 0;  // h1 row 0 (32 B)
  if (tid < 16) {  // combined cvec + distance bias
    float dx = anchor[(size_t)b * 3 + 0] - ledp[tid * 3 + 0];
    float dy = anchor[(size_t)b * 3 + 1] - ledp[tid * 3 + 1];
    float dz = anchor[(size_t)b * 3 + 2] - ledp[tid * 3 + 2];
    bias_lds[tid] = cvec[tid] - 0.5f * __logf(dx * dx + dy * dy + dz * dz + 1e-8f);
  }

  const float* xb = rss + (size_t)b * 6144;
#pragma unroll
  for (int i = 0; i < 6; ++i) {
    int f = tid + i * 256;
    f32x4 v = ((const f32x4*)xb)[f];
    int w = f / 3;
    int c = (f - w * 3) * 4;  // {0,4,8}
    int pk = __builtin_amdgcn_cvt_pk_fp8_f32(16.f * v[0], 16.f * v[1], 0, false);
    pk = __builtin_amdgcn_cvt_pk_fp8_f32(16.f * v[2], 16.f * v[3], pk, true);
    *(int*)(xwb + (w + 1) * 16 + c) = pk;
  }
  __syncthreads();  // barrier A

  // ---- pre-B: score A-loads early, conv1 x8, score MFMA, parts write ----
  {
    // 1) issue the 32 per-wave score loads NOW (L2-hot from staging)
    const int rcl = (a15 < 12) ? a15 : 11;
    float sav[4][8];
#pragma unroll
    for (int t = 0; t < 4; ++t) {
      const int s = 4 * t + wv;
      const float* xs = xb + (s * 32 + g * 8) * 12 + rcl;
#pragma unroll
      for (int j = 0; j < 8; ++j) sav[t][j] = xs[j * 12];
    }
    float anc0 = 0.f, anc1 = 0.f, anc2 = 0.f;
    if (wv == 0) {
      anc0 = anchor[(size_t)b * 3 + 0];
      anc1 = anchor[(size_t)b * 3 + 1];
      anc2 = anchor[(size_t)b * 3 + 2];
    }

    // 2) conv1: 8 tiles per wave (pure LDS+MFMA, overlaps the loads above)
#pragma unroll
    for (int t = 0; t < 8; ++t) {
      const int wt = wv * 8 + t;
      const int wcol = wt * 16 + a15;
      f32x4 c0 = {0.f, 0.f, 0.f, 0.f}, c1 = {0.f, 0.f, 0.f, 0.f};
#pragma unroll
      for (int s = 0; s < 2; ++s) {
        int row = wcol + 2 * s + (g >> 1);
        i64 bv = *(const i64*)(xwb + row * 16 + ((g & 1) << 3));
        c0 = mfma8(w1f[0][s], bv, c0);
        c1 = mfma8(w1f[1][s], bv, c1);
      }
      const int hrow = wcol + 1;
      const int swz = (hrow >> 2) & 3;
      const int off0 = ((((g >> 1) + 0) ^ swz) << 3) | ((g & 1) << 2);
      const int off1 = ((((g >> 1) + 2) ^ swz) << 3) | ((g & 1) << 2);
      float v0 = fmaxf(fmaf(c0[0], 0.00390625f, b1v[0][0]), 0.f);
      float v1 = fmaxf(fmaf(c0[1], 0.00390625f, b1v[0][1]), 0.f);
      float v2 = fmaxf(fmaf(c0[2], 0.00390625f, b1v[0][2]), 0.f);
      float v3 = fmaxf(fmaf(c0[3], 0.00390625f, b1v[0][3]), 0.f);
      int pk0 = __builtin_amdgcn_cvt_pk_fp8_f32(v0, v1, 0, false);
      pk0 = __builtin_amdgcn_cvt_pk_fp8_f32(v2, v3, pk0, true);
      *(int*)(h1b + hrow * 32 + off0) = pk0;
      v0 = fmaxf(fmaf(c1[0], 0.00390625f, b1v[1][0]), 0.f);
      v1 = fmaxf(fmaf(c1[1], 0.00390625f, b1v[1][1]), 0.f);
      v2 = fmaxf(fmaf(c1[2], 0.00390625f, b1v[1][2]), 0.f);
      v3 = fmaxf(fmaf(c1[3], 0.00390625f, b1v[1][3]), 0.f);
      int pk1 = __builtin_amdgcn_cvt_pk_fp8_f32(v0, v1, 0, false);
      pk1 = __builtin_amdgcn_cvt_pk_fp8_f32(v2, v3, pk1, true);
      *(int*)(h1b + hrow * 32 + off1) = pk1;
    }

    // 3) score MFMA on the prefetched values
    const bf16* MgR = Mg + a15 * MK;
    f32x4 sac = {0.f, 0.f, 0.f, 0.f};
#pragma unroll
    for (int t = 0; t < 4; ++t) {
      const int s = 4 * t + wv;
      bf16x8 av;
#pragma unroll
      for (int j = 0; j < 8; ++j) av[j] = (bf16)sav[t][j];
      bf16x8 bm = *(const bf16x8*)&MgR[s * 32 + g * 8];
      sac = mfma16(av, bm, sac);
    }
    if (wv == 0) {  // k-step 16: slots 512..514 = anchor; rest zero
      bf16x8 av = {(bf16)0.f, (bf16)0.f, (bf16)0.f, (bf16)0.f,
                   (bf16)0.f, (bf16)0.f, (bf16)0.f, (bf16)0.f};
      if (g == 0) { av[0] = (bf16)anc0; av[1] = (bf16)anc1; av[2] = (bf16)anc2; }
      bf16x8 bm = *(const bf16x8*)&MgR[512 + g * 8];
      sac = mfma16(av, bm, sac);
    }
#pragma unroll
    for (int r = 0; r < 4; ++r)
      parts[wv * 256 + (g * 4 + r) * 16 + a15] = sac[r];
  }
  __syncthreads();  // barrier B  (xw8 dead from here; tfp/comb overlay it)

  // ---- post-B: conv2 (fp8 MFMA, swizzled h1 reads) + pooled mean ----
  {
    float tacc[4][4] = {{0.f, 0.f, 0.f, 0.f}, {0.f, 0.f, 0.f, 0.f},
                        {0.f, 0.f, 0.f, 0.f}, {0.f, 0.f, 0.f, 0.f}};
#pragma unroll
    for (int pti = 0; pti < 4; ++pti) {
      const int p = (wv * 4 + pti) * 16 + a15;
      f32x4 cc0 = {0.f, 0.f, 0.f, 0.f}, cc1 = {0.f, 0.f, 0.f, 0.f};
      f32x4 cc2 = {0.f, 0.f, 0.f, 0.f}, cc3 = {0.f, 0.f, 0.f, 0.f};
#pragma unroll
      for (int s = 0; s < 3; ++s) {
        const int rho = 2 * p + s;
        i64 hv = *(const i64*)(h1b + rho * 32 + ((g ^ ((rho >> 2) & 3)) << 3));
        cc0 = mfma8(w2f[0][s], hv, cc0);
        cc1 = mfma8(w2f[1][s], hv, cc1);
        cc2 = mfma8(w2f[2][s], hv, cc2);
        cc3 = mfma8(w2f[3][s], hv, cc3);
      }
#pragma unroll
      for (int r = 0; r < 4; ++r) {
        tacc[0][r] += fmaxf(cc0[r] + b2s[0][r], 0.f);
        tacc[1][r] += fmaxf(cc1[r] + b2s[1][r], 0.f);
        tacc[2][r] += fmaxf(cc2[r] + b2s[2][r], 0.f);
        tacc[3][r] += fmaxf(cc3[r] + b2s[3][r], 0.f);
      }
    }
#pragma unroll
    for (int o = 0; o < 4; ++o)
#pragma unroll
      for (int r = 0; r < 4; ++r) {
        float v = tacc[o][r];
        v += __shfl_xor(v, 1, 16);
        v += __shfl_xor(v, 2, 16);
        v += __shfl_xor(v, 4, 16);
        v += __shfl_xor(v, 8, 16);
        if (a15 == 0) tfp[wv * 64 + o * 16 + g * 4 + r] = v;
      }
  }
  __syncthreads();  // barrier C

  // ---- post-C: softmax + in-group s_agg (tid<192) || t_feat (tid>=192) ----
  if (tid < 192) {
    const int r = tid >> 4, n = tid & 15;
    float s = parts[tid] + parts[256 + tid] + parts[512 + tid] + parts[768 + tid];
    s += bias_lds[n];
    if (fmask[r * 16 + n] == 0) s = -FLT_MAX;
    float mx = s;
    mx = fmaxf(mx, __shfl_xor(mx, 1, 16));
    mx = fmaxf(mx, __shfl_xor(mx, 2, 16));
    mx = fmaxf(mx, __shfl_xor(mx, 4, 16));
    mx = fmaxf(mx, __shfl_xor(mx, 8, 16));
    float ev = __expf(s - mx);
    float sm = ev;
    sm += __shfl_xor(sm, 1, 16);
    sm += __shfl_xor(sm, 2, 16);
    sm += __shfl_xor(sm, 4, 16);
    sm += __shfl_xor(sm, 8, 16);
    const float attv = ev / sm;
#pragma unroll
    for (int f = 0; f < 8; ++f) {  // s_agg via 16-lane reduce, no att array
      float c = attv * ledf[n * 8 + f];
      c += __shfl_xor(c, 1, 16);
      c += __shfl_xor(c, 2, 16);
      c += __shfl_xor(c, 4, 16);
      c += __shfl_xor(c, 8, 16);
      if (n == f) sagg[r * 8 + f] = c;
    }
  } else {
    const int t64 = tid - 192;
    comb[t64] = (tfp[t64] + tfp[64 + t64] + tfp[128 + t64] + tfp[192 + t64]) *
                (1.f / 4096.f);  // /256 mean * /16 conv2 fp8 scale
  }
  __syncthreads();  // barrier D

  // ---- post-D: spread s_feat ----
  {
    const int o = tid >> 2, q = tid & 3;
    float acc = 0.f;
    const f32x4* rwv = (const f32x4*)(rw + o * 96 + q * 24);
    const f32x4* sv = (const f32x4*)(sagg + q * 24);
#pragma unroll
    for (int i = 0; i < 6; ++i) {
      f32x4 a = rwv[i], s = sv[i];
      acc += a[0] * s[0] + a[1] * s[1] + a[2] * s[2] + a[3] * s[3];
    }
    acc += __shfl_xor(acc, 1, 4);
    acc += __shfl_xor(acc, 2, 4);
    if (q == 0) comb[64 + o] = fmaxf(acc + rb[o], 0.f);
  }
  __syncthreads();  // barrier E

  // ---- post-E: spread fusion GEMV: out = fus_w @ comb + fus_b ----
  {
    const int o = tid >> 2, q = tid & 3;
    float acc = 0.f;
    const f32x4* fwv = (const f32x4*)(fw + o * 128 + q * 32);
    const f32x4* cv = (const f32x4*)(comb + q * 32);
#pragma unroll
    for (int i = 0; i < 8; ++i) {
      f32x4 a = fwv[i], c = cv[i];
      acc += a[0] * c[0] + a[1] * c[1] + a[2] * c[2] + a[3] * c[3];
    }
    acc += __shfl_xor(acc, 1, 4);
    acc += __shfl_xor(acc, 2, 4);
    if (q == 0) out[(size_t)b * 64 + o] = acc + fb[o];
  }
}

extern "C" void kernel_launch(void* const* d_in, const int* in_sizes, int n_in,
                              void* d_out, int out_size, void* d_ws, size_t ws_size,
                              hipStream_t stream) {
  (void)in_sizes; (void)n_in; (void)out_size; (void)ws_size;
  const float* rss   = (const float*)d_in[0];
  const float* anch  = (const float*)d_in[1];
  const float* ledf  = (const float*)d_in[2];
  const float* ledp  = (const float*)d_in[3];
  const int*   fmask = (const int*)d_in[4];
  const float* c1w = (const float*)d_in[5];
  const float* c1b = (const float*)d_in[6];
  const float* c2w = (const float*)d_in[7];
  const float* c2b = (const float*)d_in[8];
  const float* qw  = (const float*)d_in[9];
  const float* qb  = (const float*)d_in[10];
  const float* kw  = (const float*)d_in[11];
  const float* kb  = (const float*)d_in[12];
  const float* rw  = (const float*)d_in[13];
  const float* rb  = (const float*)d_in[14];
  const float* fw  = (const float*)d_in[15];
  const float* fb  = (const float*)d_in[16];
  float* outp = (float*)d_out;
  char* ws = (char*)d_ws;

  acek_pre<<<35, 256, 0, stream>>>(ledf, ledp, qw, qb, kw, kb, c1w, c2w, ws);
  acek_main<<<8192, 256, 0, stream>>>(
      rss, anch, ledf, ledp, fmask, c1b, c2b, rw, rb, fw, fb,
      (const bf16*)(ws + WS_MG), (const float*)(ws + WS_CVEC),
      (const i64*)(ws + WS_W1F), (const i64*)(ws + WS_W2F), outp);
}